// Round 2
// baseline (137.687 us; speedup 1.0000x reference)
//
#include <hip/hip_runtime.h>
#include <hip/hip_bf16.h>

// Problem constants (JointAnfisNet)
#define BATCH      16384
#define N_IN       6
#define N_MF       5
#define N_FUZZ     30      // N_IN * N_MF
#define N_RULES    2048
#define N_OUT_MEM  12

// Decomposition (identical to verified 80.6us kernel):
//   256 rows/block, 4 rows per lane packed as f16x4 (uint2) -> one ds_read_b64
//   serves 4 rows. Rules split 4 ways across blocks; grid = 256 blocks.
// NEW this round (R2): finalize folded into main via last-block-per-rowgroup
//   atomics (NO cooperative launch -- R1 showed hipLaunchCooperativeKernel
//   breaks graph capture, +40us). prep zeroes acc/cnt each iteration, so the
//   poisoned workspace can't corrupt the rendezvous. Dispatches: 3 -> 2.
#define ROWS_PB    256
#define SPLITS     4
#define RULES_PB   (N_RULES / SPLITS)     // 512
#define THREADS    1024
#define WAVES      16
#define RULES_PW   (RULES_PB / WAVES)     // 32
#define ROWGROUPS  (BATCH / ROWS_PB)      // 64

// d_ws layout (we use ~230 KB of the ~256 MB workspace)
#define WS_PACKED_OFF  0                       // u32[2048]          = 8 KB
#define WS_OW_OFF      8192                    // float2[2048]       = 16 KB
#define WS_ACC_OFF     24576                   // f32[3*BATCH]       = 192 KB
#define WS_CNT_OFF     221184                  // int[ROWGROUPS]     = 256 B

typedef _Float16 f16x2 __attribute__((ext_vector_type(2)));

// ---------------------------------------------------------------------------
// Deterministic dtype probe: mf_scales is genuinely in [0.5, 1.5]. Interpret
// its first 60 bytes as 30 bf16 halves; all-in-[0.4,1.6] => bf16 data.
// ---------------------------------------------------------------------------
__device__ inline int probe_is_bf16(const void* mfs) {
    const unsigned int* w = (const unsigned int*)mfs;
    int ok = 1;
    for (int k = 0; k < 15; ++k) {
        const unsigned int v = w[k];
        const float lo = __uint_as_float(v << 16);
        const float hi = __uint_as_float(v & 0xffff0000u);
        if (!(lo >= 0.4f && lo <= 1.6f && hi >= 0.4f && hi <= 1.6f)) { ok = 0; break; }
    }
    return ok;
}

// ---------------------------------------------------------------------------
// Prep: pack each rule's 6 MF indices (5 bits each) into u32, pre-gather
// out_centers[output_rules] -> float2. ALSO zeroes the accumulator arrays and
// per-rowgroup counters used by main's fused finalize (workspace is poisoned
// between iterations; prep runs before main in-stream, so zeros are visible
// via the kernel-boundary release/acquire).
// ---------------------------------------------------------------------------
__global__ void anfis_prep(const int* __restrict__ input_rules,
                           const int* __restrict__ output_rules,
                           const void* __restrict__ oc_,
                           const void* __restrict__ mfs_,
                           unsigned int* __restrict__ packed,
                           float2* __restrict__ ow,
                           float* __restrict__ acc,
                           int* __restrict__ cnt) {
    __shared__ int flag;
    if (threadIdx.x == 0) flag = probe_is_bf16(mfs_);
    __syncthreads();
    const bool is_bf16 = (flag != 0);

    const int r = blockIdx.x * blockDim.x + threadIdx.x;   // 0..2047

    // zero accumulators (3*16384 floats) + counters (64 ints)
    for (int i = r; i < 3 * BATCH; i += N_RULES) acc[i] = 0.0f;
    if (r < ROWGROUPS) cnt[r] = 0;

    if (r >= N_RULES) return;
    const int* rp = input_rules + r * N_IN;
    unsigned int p = 0;
#pragma unroll
    for (int i = 0; i < N_IN; ++i) p |= ((unsigned int)rp[i] & 31u) << (5 * i);
    packed[r] = p;

    const int o0i = output_rules[2 * r + 0];
    const int o1i = output_rules[2 * r + 1];
    float o0, o1;
    if (is_bf16) {
        const unsigned short* oc = (const unsigned short*)oc_;
        o0 = __uint_as_float((unsigned int)oc[o0i] << 16);
        o1 = __uint_as_float((unsigned int)oc[o1i] << 16);
    } else {
        const float* oc = (const float*)oc_;
        o0 = oc[o0i]; o1 = oc[o1i];
    }
    ow[r] = make_float2(o0, o1);
}

// ---------------------------------------------------------------------------
// Main: block = (row group g: 256 rows) x (rule split s: 512 rules).
//   lane (0..63) covers rows {l, l+64, l+128, l+192} packed as f16x4 in uint2.
//   wave (0..15) handles 32 rules; rule index wave-uniform -> packed/ow come
//   in via the scalar pipe; the 6 fuzz gathers are ds_read_b64, conflict-free.
// Tail: block reduce -> device-scope atomicAdd into acc -> last block per
//   rowgroup (counter rendezvous) re-reads acc coherently and finalizes.
// ---------------------------------------------------------------------------
__global__ __launch_bounds__(THREADS, 4)
void anfis_main(const void* __restrict__ x_,
                const void* __restrict__ mfc_,
                const void* __restrict__ mfs_,
                const unsigned int* __restrict__ packed,
                const float2* __restrict__ ow,
                float* __restrict__ acc,
                int* __restrict__ cnt,
                void* __restrict__ out_) {
    __shared__ float xs[ROWS_PB * N_IN];       // 6 KB staged x
    __shared__ float2 cinv[N_FUZZ];            // (center, 1/scale)
    __shared__ uint2 fuzz4[N_FUZZ][64];        // 15 KB, 4 rows/lane as f16x4
    __shared__ float pl1[WAVES][ROWS_PB];      // 16 KB
    __shared__ float pd0[WAVES][ROWS_PB];      // 16 KB
    __shared__ float pd1[WAVES][ROWS_PB];      // 16 KB
    __shared__ int flag;
    __shared__ int lastBlk;

    const int t     = threadIdx.x;
    const int g     = blockIdx.x >> 2;         // row group 0..63
    const int split = blockIdx.x & 3;          // rule split 0..3
    const int row0  = g * ROWS_PB;

    if (t == 0) flag = probe_is_bf16(mfs_);
    __syncthreads();
    const bool is_bf16 = (flag != 0);

    // ---- stage x rows + MF params into LDS ----
    if (is_bf16) {
        const unsigned short* xp = (const unsigned short*)x_ + row0 * N_IN;
        for (int i = t; i < ROWS_PB * N_IN; i += THREADS)
            xs[i] = __uint_as_float((unsigned int)xp[i] << 16);
    } else {
        const float* xp = (const float*)x_ + row0 * N_IN;
        for (int i = t; i < ROWS_PB * N_IN; i += THREADS) xs[i] = xp[i];
    }
    if (t < N_FUZZ) {
        float c, s;
        if (is_bf16) {
            c = __uint_as_float((unsigned int)((const unsigned short*)mfc_)[t] << 16);
            s = __uint_as_float((unsigned int)((const unsigned short*)mfs_)[t] << 16);
        } else {
            c = ((const float*)mfc_)[t];
            s = ((const float*)mfs_)[t];
        }
        cinv[t] = make_float2(c, 1.0f / s);
    }
    __syncthreads();

    // ---- fuzzify: 30 x 64 uint2 entries, each = 4 rows' exp(-z^2) as f16 ----
    for (int e = t; e < N_FUZZ * 64; e += THREADS) {
        const int v    = e >> 6;    // MF value index 0..29
        const int lane = e & 63;
        const int i    = v / N_MF;  // input index
        const float2 ci = cinv[v];
        float f[4];
#pragma unroll
        for (int k = 0; k < 4; ++k) {
            const float z = (xs[(lane + 64 * k) * N_IN + i] - ci.x) * ci.y;
            f[k] = __expf(-z * z);
        }
        f16x2 a = { (_Float16)f[0], (_Float16)f[1] };   // rows lane, lane+64
        f16x2 b = { (_Float16)f[2], (_Float16)f[3] };   // rows lane+128, +192
        uint2 u;
        u.x = __builtin_bit_cast(unsigned int, a);
        u.y = __builtin_bit_cast(unsigned int, b);
        fuzz4[v][lane] = u;
    }
    __syncthreads();

    // ---- rule loop: wave-uniform r -> scalar packed/ow, 6 b64 gathers ----
    const int lane = t & 63;
    const int wave = __builtin_amdgcn_readfirstlane(t >> 6);
    const uint2* fz = &fuzz4[0][0];

    float l1[4] = {0.f, 0.f, 0.f, 0.f};
    float d0[4] = {0.f, 0.f, 0.f, 0.f};
    float d1[4] = {0.f, 0.f, 0.f, 0.f};

    const int rbase = split * RULES_PB + wave * RULES_PW;
#pragma unroll 4
    for (int j = 0; j < RULES_PW; ++j) {
        const int r = rbase + j;
        const unsigned int p = packed[r];   // uniform -> scalar load
        const float2 o = ow[r];             // uniform -> scalar load
        const uint2 g0 = fz[((p      ) & 31u) * 64 + lane];
        const uint2 g1 = fz[((p >> 5 ) & 31u) * 64 + lane];
        const uint2 g2 = fz[((p >> 10) & 31u) * 64 + lane];
        const uint2 g3 = fz[((p >> 15) & 31u) * 64 + lane];
        const uint2 g4 = fz[((p >> 20) & 31u) * 64 + lane];
        const uint2 g5 = fz[((p >> 25) & 31u) * 64 + lane];
        f16x2 wa = __builtin_elementwise_min(__builtin_bit_cast(f16x2, g0.x),
                                             __builtin_bit_cast(f16x2, g1.x));
        wa = __builtin_elementwise_min(wa, __builtin_bit_cast(f16x2, g2.x));
        wa = __builtin_elementwise_min(wa, __builtin_bit_cast(f16x2, g3.x));
        wa = __builtin_elementwise_min(wa, __builtin_bit_cast(f16x2, g4.x));
        wa = __builtin_elementwise_min(wa, __builtin_bit_cast(f16x2, g5.x));
        f16x2 wb = __builtin_elementwise_min(__builtin_bit_cast(f16x2, g0.y),
                                             __builtin_bit_cast(f16x2, g1.y));
        wb = __builtin_elementwise_min(wb, __builtin_bit_cast(f16x2, g2.y));
        wb = __builtin_elementwise_min(wb, __builtin_bit_cast(f16x2, g3.y));
        wb = __builtin_elementwise_min(wb, __builtin_bit_cast(f16x2, g4.y));
        wb = __builtin_elementwise_min(wb, __builtin_bit_cast(f16x2, g5.y));
        const float w0 = (float)wa.x, w1 = (float)wa.y;
        const float w2 = (float)wb.x, w3 = (float)wb.y;
        l1[0] += w0; d0[0] += w0 * o.x; d1[0] += w0 * o.y;
        l1[1] += w1; d0[1] += w1 * o.x; d1[1] += w1 * o.y;
        l1[2] += w2; d0[2] += w2 * o.x; d1[2] += w2 * o.y;
        l1[3] += w3; d0[3] += w3 * o.x; d1[3] += w3 * o.y;
    }
#pragma unroll
    for (int k = 0; k < 4; ++k) {
        pl1[wave][lane + 64 * k] = l1[k];
        pd0[wave][lane + 64 * k] = d0[k];
        pd1[wave][lane + 64 * k] = d1[k];
    }
    __syncthreads();

    // ---- block reduction over 16 waves; atomic-accumulate split partials ----
    if (t < ROWS_PB) {
        float a = 0.f, b = 0.f, c = 0.f;
#pragma unroll
        for (int wv = 0; wv < WAVES; ++wv) {
            a += pl1[wv][t];
            b += pd0[wv][t];
            c += pd1[wv][t];
        }
        const int row = row0 + t;
        atomicAdd(&acc[0 * BATCH + row], a);   // device-scope, cross-XCD safe
        atomicAdd(&acc[1 * BATCH + row], b);
        atomicAdd(&acc[2 * BATCH + row], c);
    }

    // ---- rendezvous: last split block for this rowgroup finalizes ----
    __threadfence();      // drain this thread's atomics (release)
    __syncthreads();      // all threads of block published
    if (t == 0) lastBlk = (atomicAdd(&cnt[g], 1) == SPLITS - 1);
    __syncthreads();

    if (lastBlk && t < ROWS_PB) {
        const int row = row0 + t;
        // coherent reads via atomic-add-zero (executes at coherence point)
        const float a = atomicAdd(&acc[0 * BATCH + row], 0.0f);
        const float b = atomicAdd(&acc[1 * BATCH + row], 0.0f);
        const float c = atomicAdd(&acc[2 * BATCH + row], 0.0f);
        const float inv = 1.0f / fmaxf(a, 1e-12f);
        const float y0 = tanhf(b * inv) * 4.00f + 0.00f;
        const float y1 = tanhf(c * inv) * 0.75f + 0.75f;
        if (is_bf16) {
            __hip_bfloat162 o;
            o.x = __float2bfloat16(y0);
            o.y = __float2bfloat16(y1);
            ((__hip_bfloat162*)out_)[row] = o;
        } else {
            ((float2*)out_)[row] = make_float2(y0, y1);
        }
    }
}

extern "C" void kernel_launch(void* const* d_in, const int* in_sizes, int n_in,
                              void* d_out, int out_size, void* d_ws, size_t ws_size,
                              hipStream_t stream) {
    (void)in_sizes; (void)n_in; (void)out_size; (void)ws_size;
    const void* x_   = d_in[0];
    const void* mfc_ = d_in[1];
    const void* mfs_ = d_in[2];
    const void* oc_  = d_in[3];
    const int* input_rules  = (const int*)d_in[4];
    const int* output_rules = (const int*)d_in[5];

    unsigned int* packed = (unsigned int*)((char*)d_ws + WS_PACKED_OFF);
    float2*       ow     = (float2*)((char*)d_ws + WS_OW_OFF);
    float*        acc    = (float*)((char*)d_ws + WS_ACC_OFF);
    int*          cnt    = (int*)((char*)d_ws + WS_CNT_OFF);

    anfis_prep<<<(N_RULES + 255) / 256, 256, 0, stream>>>(
        input_rules, output_rules, oc_, mfs_, packed, ow, acc, cnt);

    anfis_main<<<ROWGROUPS * SPLITS, THREADS, 0, stream>>>(
        x_, mfc_, mfs_, packed, ow, acc, cnt, d_out);
}

// Round 3
// 81.688 us; speedup vs baseline: 1.6855x; 1.6855x over previous
//
#include <hip/hip_runtime.h>
#include <hip/hip_bf16.h>

// Problem constants (JointAnfisNet)
#define BATCH      16384
#define N_IN       6
#define N_MF       5
#define N_FUZZ     30      // N_IN * N_MF
#define N_RULES    2048
#define N_OUT_MEM  12

// Decomposition: 256 rows/block, 4 rows per lane packed as f16x4 (uint2) ->
// one ds_read_b64 serves 4 rows. Rules split 4 ways; grid = 256 blocks.
// R3: back to the verified 3-dispatch structure (R2's atomic+threadfence tail
//   cost ~40us: device-scope fence = per-block L2 writeback on 8-XCD chip).
//   NEW: rule metadata is preloaded per-LANE (lanes 0..31 hold the wave's 32
//   rules) and broadcast with readlane at constant j. The rule loop now has
//   ZERO scalar/global loads -> s_waitcnt lgkmcnt only tracks ds_reads, so
//   gathers pipeline instead of draining at every s_load (R2 evidence:
//   VALUBusy 11%, DS busy ~11% -> stall-bound on lgkmcnt conflation).
#define ROWS_PB    256
#define SPLITS     4
#define RULES_PB   (N_RULES / SPLITS)     // 512
#define THREADS    1024
#define WAVES      16
#define RULES_PW   (RULES_PB / WAVES)     // 32
#define ROWGROUPS  (BATCH / ROWS_PB)      // 64

// d_ws layout
#define WS_PACKED_OFF  0                       // u32[2048]    = 8 KB
#define WS_OW_OFF      8192                    // float2[2048] = 16 KB
#define WS_PART_OFF    24576                   // f32[SPLITS*3*BATCH] = 768 KB

typedef _Float16 f16x2 __attribute__((ext_vector_type(2)));

// ---------------------------------------------------------------------------
// Deterministic dtype probe: mf_scales is genuinely in [0.5, 1.5]. Interpret
// its first 60 bytes as 30 bf16 halves; all-in-[0.4,1.6] => bf16 data.
// ---------------------------------------------------------------------------
__device__ inline int probe_is_bf16(const void* mfs) {
    const unsigned int* w = (const unsigned int*)mfs;
    int ok = 1;
    for (int k = 0; k < 15; ++k) {
        const unsigned int v = w[k];
        const float lo = __uint_as_float(v << 16);
        const float hi = __uint_as_float(v & 0xffff0000u);
        if (!(lo >= 0.4f && lo <= 1.6f && hi >= 0.4f && hi <= 1.6f)) { ok = 0; break; }
    }
    return ok;
}

// ---------------------------------------------------------------------------
// Prep: pack each rule's 6 MF indices (5 bits each) into u32, pre-gather
// out_centers[output_rules] -> float2.
// ---------------------------------------------------------------------------
__global__ void anfis_prep(const int* __restrict__ input_rules,
                           const int* __restrict__ output_rules,
                           const void* __restrict__ oc_,
                           const void* __restrict__ mfs_,
                           unsigned int* __restrict__ packed,
                           float2* __restrict__ ow) {
    __shared__ int flag;
    if (threadIdx.x == 0) flag = probe_is_bf16(mfs_);
    __syncthreads();
    const bool is_bf16 = (flag != 0);

    const int r = blockIdx.x * blockDim.x + threadIdx.x;
    if (r >= N_RULES) return;
    const int* rp = input_rules + r * N_IN;
    unsigned int p = 0;
#pragma unroll
    for (int i = 0; i < N_IN; ++i) p |= ((unsigned int)rp[i] & 31u) << (5 * i);
    packed[r] = p;

    const int o0i = output_rules[2 * r + 0];
    const int o1i = output_rules[2 * r + 1];
    float o0, o1;
    if (is_bf16) {
        const unsigned short* oc = (const unsigned short*)oc_;
        o0 = __uint_as_float((unsigned int)oc[o0i] << 16);
        o1 = __uint_as_float((unsigned int)oc[o1i] << 16);
    } else {
        const float* oc = (const float*)oc_;
        o0 = oc[o0i]; o1 = oc[o1i];
    }
    ow[r] = make_float2(o0, o1);
}

// ---------------------------------------------------------------------------
// Main: block = (row group g: 256 rows) x (rule split s: 512 rules).
//   lane (0..63) covers rows {l, l+64, l+128, l+192} packed as f16x4 in uint2.
//   wave (0..15) handles 32 rules. Rule metadata comes from a per-lane
//   preload + readlane broadcast: the inner loop issues ONLY ds_read_b64.
// ---------------------------------------------------------------------------
__global__ __launch_bounds__(THREADS, 4)
void anfis_main(const void* __restrict__ x_,
                const void* __restrict__ mfc_,
                const void* __restrict__ mfs_,
                const unsigned int* __restrict__ packed,
                const float2* __restrict__ ow,
                float* __restrict__ partials) {
    __shared__ float xs[ROWS_PB * N_IN];       // 6 KB staged x
    __shared__ float2 cinv[N_FUZZ];            // (center, 1/scale)
    __shared__ uint2 fuzz4[N_FUZZ][64];        // 15 KB, 4 rows/lane as f16x4
    __shared__ float pl1[WAVES][ROWS_PB];      // 16 KB
    __shared__ float pd0[WAVES][ROWS_PB];      // 16 KB
    __shared__ float pd1[WAVES][ROWS_PB];      // 16 KB
    __shared__ int flag;

    const int t     = threadIdx.x;
    const int g     = blockIdx.x >> 2;         // row group 0..63
    const int split = blockIdx.x & 3;          // rule split 0..3
    const int row0  = g * ROWS_PB;

    if (t == 0) flag = probe_is_bf16(mfs_);
    __syncthreads();
    const bool is_bf16 = (flag != 0);

    // ---- per-lane rule-metadata preload (issue EARLY, overlap with staging) --
    const int lane = t & 63;
    const int wave = __builtin_amdgcn_readfirstlane(t >> 6);
    const int rbase = split * RULES_PB + wave * RULES_PW;
    unsigned pk_v = 0u;
    float owx_v = 0.0f, owy_v = 0.0f;
    if (lane < RULES_PW) {
        pk_v = packed[rbase + lane];           // coalesced dword, lanes 0..31
        const float2 o = ow[rbase + lane];     // coalesced dwordx2
        owx_v = o.x; owy_v = o.y;
    }

    // ---- stage x rows + MF params into LDS ----
    if (is_bf16) {
        const unsigned short* xp = (const unsigned short*)x_ + row0 * N_IN;
        for (int i = t; i < ROWS_PB * N_IN; i += THREADS)
            xs[i] = __uint_as_float((unsigned int)xp[i] << 16);
    } else {
        const float* xp = (const float*)x_ + row0 * N_IN;
        for (int i = t; i < ROWS_PB * N_IN; i += THREADS) xs[i] = xp[i];
    }
    if (t < N_FUZZ) {
        float c, s;
        if (is_bf16) {
            c = __uint_as_float((unsigned int)((const unsigned short*)mfc_)[t] << 16);
            s = __uint_as_float((unsigned int)((const unsigned short*)mfs_)[t] << 16);
        } else {
            c = ((const float*)mfc_)[t];
            s = ((const float*)mfs_)[t];
        }
        cinv[t] = make_float2(c, 1.0f / s);
    }
    __syncthreads();

    // ---- fuzzify: 30 x 64 uint2 entries, each = 4 rows' exp(-z^2) as f16 ----
    for (int e = t; e < N_FUZZ * 64; e += THREADS) {
        const int v    = e >> 6;    // MF value index 0..29
        const int ln   = e & 63;
        const int i    = v / N_MF;  // input index
        const float2 ci = cinv[v];
        float f[4];
#pragma unroll
        for (int k = 0; k < 4; ++k) {
            const float z = (xs[(ln + 64 * k) * N_IN + i] - ci.x) * ci.y;
            f[k] = __expf(-z * z);
        }
        f16x2 a = { (_Float16)f[0], (_Float16)f[1] };   // rows ln, ln+64
        f16x2 b = { (_Float16)f[2], (_Float16)f[3] };   // rows ln+128, +192
        uint2 u;
        u.x = __builtin_bit_cast(unsigned int, a);
        u.y = __builtin_bit_cast(unsigned int, b);
        fuzz4[v][ln] = u;
    }
    __syncthreads();

    // ---- rule loop: readlane-broadcast metadata, 6 ds_read_b64 gathers ----
    const uint2* fz = &fuzz4[0][0];

    float l1[4] = {0.f, 0.f, 0.f, 0.f};
    float d0[4] = {0.f, 0.f, 0.f, 0.f};
    float d1[4] = {0.f, 0.f, 0.f, 0.f};

#pragma unroll
    for (int j = 0; j < RULES_PW; ++j) {
        // compile-time lane j -> v_readlane to SGPR; no memory op, no lgkmcnt
        const unsigned p = (unsigned)__builtin_amdgcn_readlane((int)pk_v, j);
        const float ox = __uint_as_float(
            (unsigned)__builtin_amdgcn_readlane((int)__float_as_uint(owx_v), j));
        const float oy = __uint_as_float(
            (unsigned)__builtin_amdgcn_readlane((int)__float_as_uint(owy_v), j));

        const uint2 g0 = fz[((p      ) & 31u) * 64 + lane];
        const uint2 g1 = fz[((p >> 5 ) & 31u) * 64 + lane];
        const uint2 g2 = fz[((p >> 10) & 31u) * 64 + lane];
        const uint2 g3 = fz[((p >> 15) & 31u) * 64 + lane];
        const uint2 g4 = fz[((p >> 20) & 31u) * 64 + lane];
        const uint2 g5 = fz[((p >> 25) & 31u) * 64 + lane];
        f16x2 wa = __builtin_elementwise_min(__builtin_bit_cast(f16x2, g0.x),
                                             __builtin_bit_cast(f16x2, g1.x));
        wa = __builtin_elementwise_min(wa, __builtin_bit_cast(f16x2, g2.x));
        wa = __builtin_elementwise_min(wa, __builtin_bit_cast(f16x2, g3.x));
        wa = __builtin_elementwise_min(wa, __builtin_bit_cast(f16x2, g4.x));
        wa = __builtin_elementwise_min(wa, __builtin_bit_cast(f16x2, g5.x));
        f16x2 wb = __builtin_elementwise_min(__builtin_bit_cast(f16x2, g0.y),
                                             __builtin_bit_cast(f16x2, g1.y));
        wb = __builtin_elementwise_min(wb, __builtin_bit_cast(f16x2, g2.y));
        wb = __builtin_elementwise_min(wb, __builtin_bit_cast(f16x2, g3.y));
        wb = __builtin_elementwise_min(wb, __builtin_bit_cast(f16x2, g4.y));
        wb = __builtin_elementwise_min(wb, __builtin_bit_cast(f16x2, g5.y));
        const float w0 = (float)wa.x, w1 = (float)wa.y;
        const float w2 = (float)wb.x, w3 = (float)wb.y;
        l1[0] += w0; d0[0] += w0 * ox; d1[0] += w0 * oy;
        l1[1] += w1; d0[1] += w1 * ox; d1[1] += w1 * oy;
        l1[2] += w2; d0[2] += w2 * ox; d1[2] += w2 * oy;
        l1[3] += w3; d0[3] += w3 * ox; d1[3] += w3 * oy;
    }
#pragma unroll
    for (int k = 0; k < 4; ++k) {
        pl1[wave][lane + 64 * k] = l1[k];
        pd0[wave][lane + 64 * k] = d0[k];
        pd1[wave][lane + 64 * k] = d1[k];
    }
    __syncthreads();

    // ---- block reduction over 16 waves; write split partials ----
    if (t < ROWS_PB) {
        float a = 0.f, b = 0.f, c = 0.f;
#pragma unroll
        for (int wv = 0; wv < WAVES; ++wv) {
            a += pl1[wv][t];
            b += pd0[wv][t];
            c += pd1[wv][t];
        }
        const int row = row0 + t;
        partials[(split * 3 + 0) * BATCH + row] = a;
        partials[(split * 3 + 1) * BATCH + row] = b;
        partials[(split * 3 + 2) * BATCH + row] = c;
    }
}

// ---------------------------------------------------------------------------
// Finalize: sum the 4 rule-split partials per row, normalize, tanh, store.
// ---------------------------------------------------------------------------
__global__ void anfis_finalize(const float* __restrict__ partials,
                               const void* __restrict__ mfs_,
                               void* __restrict__ out_) {
    __shared__ int flag;
    if (threadIdx.x == 0) flag = probe_is_bf16(mfs_);
    __syncthreads();
    const int row = blockIdx.x * blockDim.x + threadIdx.x;
    if (row >= BATCH) return;
    float l1 = 0.f, d0 = 0.f, d1 = 0.f;
#pragma unroll
    for (int s = 0; s < SPLITS; ++s) {
        l1 += partials[(s * 3 + 0) * BATCH + row];
        d0 += partials[(s * 3 + 1) * BATCH + row];
        d1 += partials[(s * 3 + 2) * BATCH + row];
    }
    const float inv = 1.0f / fmaxf(l1, 1e-12f);
    const float y0 = tanhf(d0 * inv) * 4.00f + 0.00f;
    const float y1 = tanhf(d1 * inv) * 0.75f + 0.75f;
    if (flag) {
        __hip_bfloat162 o;
        o.x = __float2bfloat16(y0);
        o.y = __float2bfloat16(y1);
        ((__hip_bfloat162*)out_)[row] = o;
    } else {
        ((float2*)out_)[row] = make_float2(y0, y1);
    }
}

extern "C" void kernel_launch(void* const* d_in, const int* in_sizes, int n_in,
                              void* d_out, int out_size, void* d_ws, size_t ws_size,
                              hipStream_t stream) {
    (void)in_sizes; (void)n_in; (void)out_size; (void)ws_size;
    const void* x_   = d_in[0];
    const void* mfc_ = d_in[1];
    const void* mfs_ = d_in[2];
    const void* oc_  = d_in[3];
    const int* input_rules  = (const int*)d_in[4];
    const int* output_rules = (const int*)d_in[5];

    unsigned int* packed = (unsigned int*)((char*)d_ws + WS_PACKED_OFF);
    float2*       ow     = (float2*)((char*)d_ws + WS_OW_OFF);
    float*        parts  = (float*)((char*)d_ws + WS_PART_OFF);

    anfis_prep<<<(N_RULES + 255) / 256, 256, 0, stream>>>(
        input_rules, output_rules, oc_, mfs_, packed, ow);

    anfis_main<<<ROWGROUPS * SPLITS, THREADS, 0, stream>>>(
        x_, mfc_, mfs_, packed, ow, parts);

    anfis_finalize<<<BATCH / 256, 256, 0, stream>>>(parts, mfs_, d_out);
}

// Round 4
// 80.007 us; speedup vs baseline: 1.7209x; 1.0210x over previous
//
#include <hip/hip_runtime.h>
#include <hip/hip_bf16.h>

// Problem constants (JointAnfisNet)
#define BATCH      16384
#define N_IN       6
#define N_MF       5
#define N_FUZZ     30      // N_IN * N_MF
#define N_RULES    2048
#define N_OUT_MEM  12

// Decomposition: 256 rows/block, 4 rows per lane packed as f16x4 (uint2) ->
// one ds_read_b64 serves 4 rows.
// R4 changes vs R3 (81.7us):
//   1) prep folded into main: each wave inline-loads+packs its own rules'
//      metadata (contiguous 768B window, L2-resident; 64 blocks share each
//      split's rules). Dispatches 3 -> 2.
//   2) SPLITS 4 -> 8 (grid 512): LDS 71KB -> 2 blocks/CU co-resident, so one
//      block's rule-loop DS traffic overlaps the other's fuzzify/barriers
//      (R2 evidence: Occupancy 43%, main ~2x above its 8.3us DS-bytes floor).
// Rule loop itself (readlane broadcast + 6x ds_read_b64 + v_pk_min) unchanged.
#define ROWS_PB    256
#define SPLITS     8
#define RULES_PB   (N_RULES / SPLITS)     // 256
#define THREADS    1024
#define WAVES      16
#define RULES_PW   (RULES_PB / WAVES)     // 16
#define ROWGROUPS  (BATCH / ROWS_PB)      // 64

// d_ws layout: partials f32[SPLITS*3*BATCH] = 1.5 MB
#define WS_PART_OFF    0

typedef _Float16 f16x2 __attribute__((ext_vector_type(2)));

// ---------------------------------------------------------------------------
// Deterministic dtype probe: mf_scales is genuinely in [0.5, 1.5]. Interpret
// its first 60 bytes as 30 bf16 halves; all-in-[0.4,1.6] => bf16 data.
// ---------------------------------------------------------------------------
__device__ inline int probe_is_bf16(const void* mfs) {
    const unsigned int* w = (const unsigned int*)mfs;
    int ok = 1;
    for (int k = 0; k < 15; ++k) {
        const unsigned int v = w[k];
        const float lo = __uint_as_float(v << 16);
        const float hi = __uint_as_float(v & 0xffff0000u);
        if (!(lo >= 0.4f && lo <= 1.6f && hi >= 0.4f && hi <= 1.6f)) { ok = 0; break; }
    }
    return ok;
}

// ---------------------------------------------------------------------------
// Main: block = (row group g: 256 rows) x (rule split s: 256 rules).
//   lane (0..63) covers rows {l, l+64, l+128, l+192} packed as f16x4 in uint2.
//   wave (0..15) handles 16 rules. Rule metadata: lanes 0..15 inline-load the
//   raw rule tables and pack; broadcast via readlane at constant j. The inner
//   loop issues ONLY ds_read_b64 (no scalar/global loads -> lgkmcnt tracks
//   just the gathers).
// ---------------------------------------------------------------------------
__global__ __launch_bounds__(THREADS, 4)
void anfis_main(const void* __restrict__ x_,
                const void* __restrict__ mfc_,
                const void* __restrict__ mfs_,
                const void* __restrict__ oc_,
                const int* __restrict__ input_rules,
                const int* __restrict__ output_rules,
                float* __restrict__ partials) {
    __shared__ float xs[ROWS_PB * N_IN];       // 6 KB staged x
    __shared__ float2 cinv[N_FUZZ];            // (center, 1/scale)
    __shared__ uint2 fuzz4[N_FUZZ][64];        // 15 KB, 4 rows/lane as f16x4
    __shared__ float pl1[WAVES][ROWS_PB];      // 16 KB
    __shared__ float pd0[WAVES][ROWS_PB];      // 16 KB
    __shared__ float pd1[WAVES][ROWS_PB];      // 16 KB
    __shared__ int flag;

    const int t     = threadIdx.x;
    const int g     = blockIdx.x >> 3;         // row group 0..63
    const int split = blockIdx.x & 7;          // rule split 0..7
    const int row0  = g * ROWS_PB;

    if (t == 0) flag = probe_is_bf16(mfs_);
    __syncthreads();
    const bool is_bf16 = (flag != 0);

    // ---- per-lane rule-metadata inline load+pack (ex-prep kernel) ----
    const int lane = t & 63;
    const int wave = __builtin_amdgcn_readfirstlane(t >> 6);
    const int rbase = split * RULES_PB + wave * RULES_PW;
    unsigned pk_v = 0u;
    float owx_v = 0.0f, owy_v = 0.0f;
    if (lane < RULES_PW) {
        const int r = rbase + lane;
        const int* rp = input_rules + r * N_IN;     // contiguous 768B per wave
        unsigned p = 0;
#pragma unroll
        for (int i = 0; i < N_IN; ++i) p |= ((unsigned)rp[i] & 31u) << (5 * i);
        pk_v = p;
        const int o0i = output_rules[2 * r + 0];
        const int o1i = output_rules[2 * r + 1];
        if (is_bf16) {
            const unsigned short* oc = (const unsigned short*)oc_;
            owx_v = __uint_as_float((unsigned)oc[o0i] << 16);
            owy_v = __uint_as_float((unsigned)oc[o1i] << 16);
        } else {
            const float* oc = (const float*)oc_;
            owx_v = oc[o0i]; owy_v = oc[o1i];
        }
    }

    // ---- stage x rows + MF params into LDS ----
    if (is_bf16) {
        const unsigned short* xp = (const unsigned short*)x_ + row0 * N_IN;
        for (int i = t; i < ROWS_PB * N_IN; i += THREADS)
            xs[i] = __uint_as_float((unsigned int)xp[i] << 16);
    } else {
        const float* xp = (const float*)x_ + row0 * N_IN;
        for (int i = t; i < ROWS_PB * N_IN; i += THREADS) xs[i] = xp[i];
    }
    if (t < N_FUZZ) {
        float c, s;
        if (is_bf16) {
            c = __uint_as_float((unsigned int)((const unsigned short*)mfc_)[t] << 16);
            s = __uint_as_float((unsigned int)((const unsigned short*)mfs_)[t] << 16);
        } else {
            c = ((const float*)mfc_)[t];
            s = ((const float*)mfs_)[t];
        }
        cinv[t] = make_float2(c, 1.0f / s);
    }
    __syncthreads();

    // ---- fuzzify: 30 x 64 uint2 entries, each = 4 rows' exp(-z^2) as f16 ----
    for (int e = t; e < N_FUZZ * 64; e += THREADS) {
        const int v    = e >> 6;    // MF value index 0..29
        const int ln   = e & 63;
        const int i    = v / N_MF;  // input index
        const float2 ci = cinv[v];
        float f[4];
#pragma unroll
        for (int k = 0; k < 4; ++k) {
            const float z = (xs[(ln + 64 * k) * N_IN + i] - ci.x) * ci.y;
            f[k] = __expf(-z * z);
        }
        f16x2 a = { (_Float16)f[0], (_Float16)f[1] };   // rows ln, ln+64
        f16x2 b = { (_Float16)f[2], (_Float16)f[3] };   // rows ln+128, +192
        uint2 u;
        u.x = __builtin_bit_cast(unsigned int, a);
        u.y = __builtin_bit_cast(unsigned int, b);
        fuzz4[v][ln] = u;
    }
    __syncthreads();

    // ---- rule loop: readlane-broadcast metadata, 6 ds_read_b64 gathers ----
    const uint2* fz = &fuzz4[0][0];

    float l1[4] = {0.f, 0.f, 0.f, 0.f};
    float d0[4] = {0.f, 0.f, 0.f, 0.f};
    float d1[4] = {0.f, 0.f, 0.f, 0.f};

#pragma unroll
    for (int j = 0; j < RULES_PW; ++j) {
        // compile-time lane j -> v_readlane to SGPR; no memory op, no lgkmcnt
        const unsigned p = (unsigned)__builtin_amdgcn_readlane((int)pk_v, j);
        const float ox = __uint_as_float(
            (unsigned)__builtin_amdgcn_readlane((int)__float_as_uint(owx_v), j));
        const float oy = __uint_as_float(
            (unsigned)__builtin_amdgcn_readlane((int)__float_as_uint(owy_v), j));

        const uint2 g0 = fz[((p      ) & 31u) * 64 + lane];
        const uint2 g1 = fz[((p >> 5 ) & 31u) * 64 + lane];
        const uint2 g2 = fz[((p >> 10) & 31u) * 64 + lane];
        const uint2 g3 = fz[((p >> 15) & 31u) * 64 + lane];
        const uint2 g4 = fz[((p >> 20) & 31u) * 64 + lane];
        const uint2 g5 = fz[((p >> 25) & 31u) * 64 + lane];
        f16x2 wa = __builtin_elementwise_min(__builtin_bit_cast(f16x2, g0.x),
                                             __builtin_bit_cast(f16x2, g1.x));
        wa = __builtin_elementwise_min(wa, __builtin_bit_cast(f16x2, g2.x));
        wa = __builtin_elementwise_min(wa, __builtin_bit_cast(f16x2, g3.x));
        wa = __builtin_elementwise_min(wa, __builtin_bit_cast(f16x2, g4.x));
        wa = __builtin_elementwise_min(wa, __builtin_bit_cast(f16x2, g5.x));
        f16x2 wb = __builtin_elementwise_min(__builtin_bit_cast(f16x2, g0.y),
                                             __builtin_bit_cast(f16x2, g1.y));
        wb = __builtin_elementwise_min(wb, __builtin_bit_cast(f16x2, g2.y));
        wb = __builtin_elementwise_min(wb, __builtin_bit_cast(f16x2, g3.y));
        wb = __builtin_elementwise_min(wb, __builtin_bit_cast(f16x2, g4.y));
        wb = __builtin_elementwise_min(wb, __builtin_bit_cast(f16x2, g5.y));
        const float w0 = (float)wa.x, w1 = (float)wa.y;
        const float w2 = (float)wb.x, w3 = (float)wb.y;
        l1[0] += w0; d0[0] += w0 * ox; d1[0] += w0 * oy;
        l1[1] += w1; d0[1] += w1 * ox; d1[1] += w1 * oy;
        l1[2] += w2; d0[2] += w2 * ox; d1[2] += w2 * oy;
        l1[3] += w3; d0[3] += w3 * ox; d1[3] += w3 * oy;
    }
#pragma unroll
    for (int k = 0; k < 4; ++k) {
        pl1[wave][lane + 64 * k] = l1[k];
        pd0[wave][lane + 64 * k] = d0[k];
        pd1[wave][lane + 64 * k] = d1[k];
    }
    __syncthreads();

    // ---- block reduction over 16 waves; write split partials ----
    if (t < ROWS_PB) {
        float a = 0.f, b = 0.f, c = 0.f;
#pragma unroll
        for (int wv = 0; wv < WAVES; ++wv) {
            a += pl1[wv][t];
            b += pd0[wv][t];
            c += pd1[wv][t];
        }
        const int row = row0 + t;
        partials[(split * 3 + 0) * BATCH + row] = a;
        partials[(split * 3 + 1) * BATCH + row] = b;
        partials[(split * 3 + 2) * BATCH + row] = c;
    }
}

// ---------------------------------------------------------------------------
// Finalize: sum the 8 rule-split partials per row, normalize, tanh, store.
// ---------------------------------------------------------------------------
__global__ void anfis_finalize(const float* __restrict__ partials,
                               const void* __restrict__ mfs_,
                               void* __restrict__ out_) {
    __shared__ int flag;
    if (threadIdx.x == 0) flag = probe_is_bf16(mfs_);
    __syncthreads();
    const int row = blockIdx.x * blockDim.x + threadIdx.x;
    if (row >= BATCH) return;
    float l1 = 0.f, d0 = 0.f, d1 = 0.f;
#pragma unroll
    for (int s = 0; s < SPLITS; ++s) {
        l1 += partials[(s * 3 + 0) * BATCH + row];
        d0 += partials[(s * 3 + 1) * BATCH + row];
        d1 += partials[(s * 3 + 2) * BATCH + row];
    }
    const float inv = 1.0f / fmaxf(l1, 1e-12f);
    const float y0 = tanhf(d0 * inv) * 4.00f + 0.00f;
    const float y1 = tanhf(d1 * inv) * 0.75f + 0.75f;
    if (flag) {
        __hip_bfloat162 o;
        o.x = __float2bfloat16(y0);
        o.y = __float2bfloat16(y1);
        ((__hip_bfloat162*)out_)[row] = o;
    } else {
        ((float2*)out_)[row] = make_float2(y0, y1);
    }
}

extern "C" void kernel_launch(void* const* d_in, const int* in_sizes, int n_in,
                              void* d_out, int out_size, void* d_ws, size_t ws_size,
                              hipStream_t stream) {
    (void)in_sizes; (void)n_in; (void)out_size; (void)ws_size;
    const void* x_   = d_in[0];
    const void* mfc_ = d_in[1];
    const void* mfs_ = d_in[2];
    const void* oc_  = d_in[3];
    const int* input_rules  = (const int*)d_in[4];
    const int* output_rules = (const int*)d_in[5];

    float* parts = (float*)((char*)d_ws + WS_PART_OFF);

    anfis_main<<<ROWGROUPS * SPLITS, THREADS, 0, stream>>>(
        x_, mfc_, mfs_, oc_, input_rules, output_rules, parts);

    anfis_finalize<<<BATCH / 256, 256, 0, stream>>>(parts, mfs_, d_out);
}